// Round 7
// baseline (125.368 us; speedup 1.0000x reference)
//
#include <hip/hip_runtime.h>

#define NB  32
#define NLQ 64
#define NLV 128
#define NQS 512
#define NFS 1024
#define NBN 512
#define CC  2.8853900817779268f   // 2*log2(e):  exp(2x) = exp2(CC*x)

typedef float  floatx4 __attribute__((ext_vector_type(4)));
typedef __bf16 bf16x8  __attribute__((ext_vector_type(8)));
typedef unsigned short us;
typedef __attribute__((address_space(1))) const unsigned int gu32;
typedef __attribute__((address_space(3))) unsigned int lu32;

__device__ __forceinline__ us f2bf(float f) {
    unsigned int u = __float_as_uint(f);
    u += 0x7fffu + ((u >> 16) & 1u);   // round-to-nearest-even
    return (us)(u >> 16);
}
// truncating pack of two fp32 -> packed bf16x2, one v_perm_b32
__device__ __forceinline__ unsigned int pktrunc(float lo, float hi) {
    return __builtin_amdgcn_perm(__float_as_uint(hi), __float_as_uint(lo), 0x07060302u);
}
__device__ __forceinline__ float blo(unsigned int u) {
    return __uint_as_float(u << 16);
}
__device__ __forceinline__ float bhi(unsigned int u) {
    return __uint_as_float(u & 0xffff0000u);
}

// ---------------- convert: fp32 -> bf16 (phr,vis,W,U); also sgf[:, :512]=phr
#define PHR4 262144
#define VIS4 1048576
#define WW4  65536
#define UU4  131072
#define TOT4 (PHR4 + VIS4 + WW4 + UU4)   // 1,507,328 float4s

__global__ __launch_bounds__(256) void convert_bf16(
    const float* __restrict__ phr, const float* __restrict__ vis,
    const float* __restrict__ W,   const float* __restrict__ U,
    us* __restrict__ phr_b, us* __restrict__ vis_b,
    us* __restrict__ W_b,   us* __restrict__ U_b,
    float* __restrict__ out_sgf)
{
    int i = blockIdx.x * 256 + threadIdx.x;
    if (i >= TOT4) return;
    const float* src; us* dst; int o;
    if (i < PHR4)              { src = phr; dst = phr_b; o = i; }
    else if (i < PHR4 + VIS4)  { src = vis; dst = vis_b; o = i - PHR4; }
    else if (i < PHR4 + VIS4 + WW4) { src = W; dst = W_b; o = i - PHR4 - VIS4; }
    else                       { src = U; dst = U_b; o = i - PHR4 - VIS4 - WW4; }
    float4 v = ((const float4*)src)[o];
    uint2 r = { pktrunc(v.x, v.y), pktrunc(v.z, v.w) };
    *(uint2*)(dst + (size_t)o * 4) = r;
    if (i < PHR4) {   // concat left half: sgf[row, 0:512] = phr (fp32, exact)
        int row = o >> 7, c4 = o & 127;
        ((float4*)out_sgf)[(size_t)row * 384 + c4] = v;
    }
}

// ---------------- GEMM: 64x64 tile, K-tile 32, bf16 in, global_load_lds -----
// Staging: 1 global_load_lds dwordx4 per thread per matrix per K-tile, with
// pre-swizzled per-lane SOURCE address + linear LDS dest (m173 pattern).
// Swizzle: 16B chunk (row, col16) lives at slot = (col16 + row + (row>>2)) & 3
// -> frag ds_read_b128 is <=2-way bank-aliased (free).
// mode Yq (whYp != null): C = exp2(CC*(acc+bias)) stored FP32 to whY[2048][512]
// mode Yv: C = exp2(CC*acc) stored bf16 TRANSPOSED to uvYT[b][n][v] via LDS
//   transpose (coalesced stores).
__device__ __forceinline__ void gemm64(
    us* smem,                             // >= 4608 us
    const us* __restrict__ A, const us* __restrict__ Bt,
    const float* __restrict__ bias,
    float* __restrict__ whYp, us* __restrict__ uvYTp,
    int K, int bx, int by)
{
    us* As = smem;                        // 2048 us (4 KB), swizzled
    us* Bs = smem + 2048;
    const int tid  = threadIdx.x;
    const int m0   = bx * 64;
    const int n0   = by * 64;
    const int wave = tid >> 6;
    const int lane = tid & 63;
    const int wm   = (wave >> 1) * 32;
    const int wn   = (wave & 1) * 32;
    const int fm   = lane & 15;
    const int c16  = lane >> 4;           // logical col16 of this lane's frag

    // staging chunk = tid: row = tid>>2, slot = tid&3; inverse swizzle -> src col
    const int srow   = tid >> 2;
    const int scol16 = ((tid & 3) - srow - (srow >> 2)) & 3;
    const us* ga = A  + (size_t)(m0 + srow) * K + scol16 * 8;
    const us* gb = Bt + (size_t)(n0 + srow) * K + scol16 * 8;

    floatx4 acc[2][2] = {};
    for (int k0 = 0; k0 < K; k0 += 32) {
        __syncthreads();                  // prior frag reads done
        __builtin_amdgcn_global_load_lds((gu32*)(ga + k0),
                                         (lu32*)(As + wave * 512), 16, 0, 0);
        __builtin_amdgcn_global_load_lds((gu32*)(gb + k0),
                                         (lu32*)(Bs + wave * 512), 16, 0, 0);
        __syncthreads();                  // drains vmcnt -> tile ready
        bf16x8 am[2], bn[2];
        #pragma unroll
        for (int i = 0; i < 2; ++i) {
            int r  = wm + 16 * i + fm;
            int sl = (c16 + r + (r >> 2)) & 3;
            am[i] = *(const bf16x8*)(As + r * 32 + sl * 8);
        }
        #pragma unroll
        for (int j = 0; j < 2; ++j) {
            int r  = wn + 16 * j + fm;
            int sl = (c16 + r + (r >> 2)) & 3;
            bn[j] = *(const bf16x8*)(Bs + r * 32 + sl * 8);
        }
        #pragma unroll
        for (int i = 0; i < 2; ++i)
            #pragma unroll
            for (int j = 0; j < 2; ++j)
                acc[i][j] = __builtin_amdgcn_mfma_f32_16x16x32_bf16(am[i], bn[j], acc[i][j], 0, 0, 0);
    }

    // C/D layout: col = lane&15, row = (lane>>4)*4 + reg
    const int cr = (lane >> 4) * 4;
    const int cc = lane & 15;
    if (whYp) {
        #pragma unroll
        for (int j = 0; j < 2; ++j) {
            int gn = n0 + wn + 16 * j + cc;
            float bj = bias[gn];
            #pragma unroll
            for (int i = 0; i < 2; ++i)
                #pragma unroll
                for (int r = 0; r < 4; ++r) {
                    int gm = m0 + wm + 16 * i + cr + r;
                    whYp[(size_t)gm * NBN + gn] =
                        __builtin_amdgcn_exp2f(CC * (acc[i][j][r] + bj));
                }
        }
    } else {
        // ---- LDS transpose epilogue: Cs[n_local][v_local], stride 72 us ----
        us* Cs = smem;                     // 64*72 = 4608 us
        __syncthreads();                   // all MFMA LDS reads done
        #pragma unroll
        for (int i = 0; i < 2; ++i)
            #pragma unroll
            for (int j = 0; j < 2; ++j) {
                int nl = wn + 16 * j + cc;
                int vl = wm + 16 * i + cr;
                #pragma unroll
                for (int r = 0; r < 4; ++r)
                    Cs[nl * 72 + vl + r] =
                        f2bf(__builtin_amdgcn_exp2f(CC * acc[i][j][r]));
            }
        __syncthreads();
        const int bb    = m0 >> 7;         // batch
        const int vbase = m0 & 127;        // 0 or 64
        const int nl    = tid >> 2;        // 0..63
        const int vc    = (tid & 3) * 16;  // 16-v chunk
        uint4 t0 = *(const uint4*)(Cs + nl * 72 + vc);
        uint4 t1 = *(const uint4*)(Cs + nl * 72 + vc + 8);
        us* dst = uvYTp + ((size_t)bb * NBN + n0 + nl) * NLV + vbase + vc;
        *(uint4*)dst       = t0;
        *(uint4*)(dst + 8) = t1;
    }
}

// blocks 0..255: Yq (M=2048,K=512, nbx=32); 256..767: Yv (M=4096,K=1024, nbx=64)
__global__ __launch_bounds__(256) void gemm_both(
    const us* __restrict__ phr_b, const us* __restrict__ W_b,
    const float* __restrict__ bias,
    const us* __restrict__ vis_b, const us* __restrict__ U_b,
    float* __restrict__ whY, us* __restrict__ uvYT)
{
    __shared__ __align__(16) us smem[4608];
    int blk = blockIdx.x;
    if (blk < 256) {
        int bx = blk % 32, by = blk / 32;
        gemm64(smem, phr_b, W_b, bias, whY, nullptr, NQS, bx, by);
    } else {
        blk -= 256;
        int bx = blk % 64, by = blk / 64;
        gemm64(smem, vis_b, U_b, bias, nullptr, uvYT, NFS, bx, by);
    }
}

// ---------------- energize: in-thread n-reduction, paired rcp ---------------
// block = (b, q-quad), 512 threads, 8 waves = n-eighths. lane owns v-pair.
//   w0/d0 + w1/d1 = (w0*d1 + w1*d0) / (d0*d1)   (d >= 1, overflow -> 0, safe)
__global__ __launch_bounds__(512) void energize(
    const float* __restrict__ whY,    // [2048][512] fp32 = exp(2(Wh+b))
    const us* __restrict__ uvYT,      // [32][512][128] bf16 = exp(2Uv), [n][v]
    const float* __restrict__ wvec,   // [512]
    float* __restrict__ out_w, float* __restrict__ out_e,
    us* __restrict__ p_bf, us* __restrict__ p_lo)   // [2048][128]
{
    const float LOG2E = 1.4426950408889634f;
    int blk = blockIdx.x;
    blk = (blk & 7) * 64 + (blk >> 3);    // bijective XCD swizzle (512 = 8*64)
    const int b    = blk >> 4;            // b-major: 16 blocks share uvYT[b]
    const int qq4  = blk & 15;
    const int tid  = threadIdx.x;
    const int wave = __builtin_amdgcn_readfirstlane(tid >> 6);  // n-eighth 0..7
    const int lane = tid & 63;
    const int q0   = qq4 * 4;

    __shared__ float part[4][8][NLV];     // [q][n-eighth][v] = 16 KB

    // sumw (once per wave)
    float4 sw0 = *(const float4*)(wvec + lane * 8);
    float4 sw1 = *(const float4*)(wvec + lane * 8 + 4);
    float sumw = sw0.x + sw0.y + sw0.z + sw0.w + sw1.x + sw1.y + sw1.z + sw1.w;
    #pragma unroll
    for (int off = 32; off; off >>= 1) sumw += __shfl_xor(sumw, off);

    const float* yqp = whY + (size_t)(b * NLQ + q0) * NBN + wave * 64;
    const float* wp  = wvec + wave * 64;
    const us*    uvp = uvYT + ((size_t)b * NBN + wave * 64) * NLV + 2 * lane;

    float acc[4][2] = {};
    #pragma unroll 2
    for (int nc = 0; nc < 64; nc += 8) {
        unsigned int yv[8];
        #pragma unroll
        for (int k = 0; k < 8; ++k)
            yv[k] = *(const unsigned int*)(uvp + (size_t)(nc + k) * NLV);
        #pragma unroll
        for (int kk = 0; kk < 4; ++kk) {
            const int k0 = nc + 2 * kk, k1 = k0 + 1;
            float x0a = blo(yv[2 * kk]),     x0b = bhi(yv[2 * kk]);     // n=k0
            float x1a = blo(yv[2 * kk + 1]), x1b = bhi(yv[2 * kk + 1]); // n=k1
            float w0 = wp[k0], w1 = wp[k1];                 // uniform -> SGPR
            #pragma unroll
            for (int q = 0; q < 4; ++q) {
                float y0 = yqp[q * NBN + k0];               // uniform -> SGPR
                float y1 = yqp[q * NBN + k1];
                float d0a = fmaf(x0a, y0, 1.f), d1a = fmaf(x1a, y1, 1.f);
                float d0b = fmaf(x0b, y0, 1.f), d1b = fmaf(x1b, y1, 1.f);
                float numa = fmaf(w0, d1a, w1 * d0a);
                float numb = fmaf(w0, d1b, w1 * d0b);
                acc[q][0] = fmaf(numa, __builtin_amdgcn_rcpf(d0a * d1a), acc[q][0]);
                acc[q][1] = fmaf(numb, __builtin_amdgcn_rcpf(d0b * d1b), acc[q][1]);
            }
        }
    }
    #pragma unroll
    for (int q = 0; q < 4; ++q) {
        float2 t = { acc[q][0], acc[q][1] };
        *(float2*)&part[q][wave][2 * lane] = t;
    }
    __syncthreads();

    // softmax: wave w handles q = w (4 q on waves 0..3)
    if (wave < 4) {
        const int q = wave;
        float s0 = 0.f, s1 = 0.f;
        #pragma unroll
        for (int nq = 0; nq < 8; ++nq) {
            s0 += part[q][nq][2 * lane];
            s1 += part[q][nq][2 * lane + 1];
        }
        float e0 = sumw - 2.f * s0;
        float e1 = sumw - 2.f * s1;
        float m = fmaxf(e0, e1);
        #pragma unroll
        for (int off = 32; off; off >>= 1) m = fmaxf(m, __shfl_xor(m, off));
        float x0 = __builtin_amdgcn_exp2f((e0 - m) * LOG2E);
        float x1 = __builtin_amdgcn_exp2f((e1 - m) * LOG2E);
        float ss = x0 + x1;
        #pragma unroll
        for (int off = 32; off; off >>= 1) ss += __shfl_xor(ss, off);
        float inv = __builtin_amdgcn_rcpf(ss);
        float p0 = x0 * inv, p1 = x1 * inv;

        const size_t row = (size_t)(b * NLQ + q0 + q);
        float2 ep = { e0, e1 };
        float2 pp = { p0, p1 };
        *(float2*)(out_e + row * NLV + 2 * lane) = ep;
        *(float2*)(out_w + row * NLV + 2 * lane) = pp;
        // bf16 p + bf16 correction (restores fp32 accuracy in the MFMA)
        unsigned int pb0 = f2bf(p0), pb1 = f2bf(p1);
        float lo0 = p0 - __uint_as_float(pb0 << 16);
        float lo1 = p1 - __uint_as_float(pb1 << 16);
        unsigned int lb0 = f2bf(lo0), lb1 = f2bf(lo1);
        *(unsigned int*)(p_bf + row * NLV + 2 * lane) = pb0 | (pb1 << 16);
        *(unsigned int*)(p_lo + row * NLV + 2 * lane) = lb0 | (lb1 << 16);
    }
}

// ---------------- aligned via MFMA: out = (P + P_lo) . V ---------------------
// block = (b, f-tile of 64). Stages its V slice from bf16 vis_b (half the
// fetch of fp32 vis; identical truncation numerics), LDS-transposed to
// Vs[f][v] (pad 136). A-frags (P) from L2; B-frags from LDS.
__global__ __launch_bounds__(256) void aligned_mfma(
    const us* __restrict__ p_bf, const us* __restrict__ p_lo,  // [2048][128]
    const us* __restrict__ vis_b,                              // [32][128][1024]
    float* __restrict__ out_sgf)
{
    int blk = blockIdx.x;
    blk = (blk & 7) * 64 + (blk >> 3);    // XCD swizzle, b-major
    const int b    = blk >> 4;
    const int ft   = blk & 15;
    const int tid  = threadIdx.x;
    const int wave = tid >> 6;
    const int lane = tid & 63;
    const int wm   = (wave >> 1) * 32;    // q offset
    const int wf   = (wave & 1) * 32;     // f offset within the 64-tile
    const int fm   = lane & 15;
    const int fko  = (lane >> 4) * 8;

    __shared__ us Vs[64][136];            // [f][v], row stride 272 B

    {   // stage V: thread owns (v = tid>>1, f-half = (tid&1)*32)
        const int v  = tid >> 1;
        const int fh = (tid & 1) * 32;
        const us* vp = vis_b + ((size_t)b * NLV + v) * NFS + ft * 64 + fh;
        #pragma unroll
        for (int r = 0; r < 8; ++r) {
            uint2 u = *(const uint2*)(vp + 4 * r);
            Vs[fh + 4 * r + 0][v] = (us)(u.x & 0xffffu);
            Vs[fh + 4 * r + 1][v] = (us)(u.x >> 16);
            Vs[fh + 4 * r + 2][v] = (us)(u.y & 0xffffu);
            Vs[fh + 4 * r + 3][v] = (us)(u.y >> 16);
        }
    }
    __syncthreads();

    floatx4 acc[2][2] = {};
    const us* pA  = p_bf + ((size_t)b * NLQ + wm + fm) * NLV + fko;
    const us* pAl = p_lo + ((size_t)b * NLQ + wm + fm) * NLV + fko;

    #pragma unroll
    for (int ks = 0; ks < 4; ++ks) {
        bf16x8 a[2], al[2], bb2[2];
        #pragma unroll
        for (int i = 0; i < 2; ++i) {
            a[i]  = *(const bf16x8*)(pA  + (size_t)i * 16 * NLV + ks * 32);
            al[i] = *(const bf16x8*)(pAl + (size_t)i * 16 * NLV + ks * 32);
        }
        #pragma unroll
        for (int j = 0; j < 2; ++j)
            bb2[j] = *(const bf16x8*)&Vs[wf + 16 * j + fm][ks * 32 + fko];
        #pragma unroll
        for (int i = 0; i < 2; ++i)
            #pragma unroll
            for (int j = 0; j < 2; ++j) {
                acc[i][j] = __builtin_amdgcn_mfma_f32_16x16x32_bf16(a[i],  bb2[j], acc[i][j], 0, 0, 0);
                acc[i][j] = __builtin_amdgcn_mfma_f32_16x16x32_bf16(al[i], bb2[j], acc[i][j], 0, 0, 0);
            }
    }

    const int cr = (lane >> 4) * 4;
    const int cc = lane & 15;
    #pragma unroll
    for (int i = 0; i < 2; ++i)
        #pragma unroll
        for (int j = 0; j < 2; ++j)
            #pragma unroll
            for (int r = 0; r < 4; ++r) {
                int q = wm + 16 * i + cr + r;
                int f = ft * 64 + wf + 16 * j + cc;
                size_t row = (size_t)b * NLQ + q;
                out_sgf[row * (NQS + NFS) + NQS + f] = acc[i][j][r];
            }
}

extern "C" void kernel_launch(void* const* d_in, const int* in_sizes, int n_in,
                              void* d_out, int out_size, void* d_ws, size_t ws_size,
                              hipStream_t stream) {
    const float* phr  = (const float*)d_in[0];
    const float* vis  = (const float*)d_in[1];
    const float* W    = (const float*)d_in[2];
    const float* U    = (const float*)d_in[3];
    const float* bias = (const float*)d_in[4];
    const float* wvec = (const float*)d_in[5];

    char* ws = (char*)d_ws;
    us* phr_b   = (us*)ws;                          // 2 MB
    us* vis_b   = (us*)(ws + (2u << 20));           // 8 MB
    us* W_b     = (us*)(ws + (10u << 20));          // 0.5 MB
    us* U_b     = (us*)(ws + (10u << 20) + (512u << 10));   // 1 MB
    float* whY  = (float*)(ws + (12u << 20));       // 4 MB [2048][512] fp32
    us* uvYT    = (us*)(ws + (16u << 20));          // 4 MB [32][512][128] bf16
    us* p_bf    = (us*)(ws + (20u << 20));          // 512 KB [2048][128]
    us* p_lo    = (us*)(ws + (20u << 20) + (512u << 10));   // 512 KB

    float* out     = (float*)d_out;
    float* out_sgf = out;
    float* out_w   = out_sgf + (size_t)NB * NLQ * (NQS + NFS);
    float* out_e   = out_w   + (size_t)NB * NLQ * NLV;

    convert_bf16<<<TOT4 / 256, 256, 0, stream>>>(
        phr, vis, W, U, phr_b, vis_b, W_b, U_b, out_sgf);
    gemm_both<<<768, 256, 0, stream>>>(phr_b, W_b, bias, vis_b, U_b, whY, uvYT);
    energize<<<512, 512, 0, stream>>>(whY, uvYT, wvec, out_w, out_e, p_bf, p_lo);
    aligned_mfma<<<512, 256, 0, stream>>>(p_bf, p_lo, vis_b, out_sgf);
}

// Round 8
// 118.852 us; speedup vs baseline: 1.0548x; 1.0548x over previous
//
#include <hip/hip_runtime.h>

#define NB  32
#define NLQ 64
#define NLV 128
#define NQS 512
#define NFS 1024
#define NBN 512
#define CC  2.8853900817779268f   // 2*log2(e):  exp(2x) = exp2(CC*x)

typedef float  floatx4 __attribute__((ext_vector_type(4)));
typedef __bf16 bf16x8  __attribute__((ext_vector_type(8)));
typedef unsigned short us;
typedef __attribute__((address_space(1))) const unsigned int gu32;
typedef __attribute__((address_space(3))) unsigned int lu32;

__device__ __forceinline__ us f2bf(float f) {
    unsigned int u = __float_as_uint(f);
    u += 0x7fffu + ((u >> 16) & 1u);   // round-to-nearest-even
    return (us)(u >> 16);
}
// truncating pack of two fp32 -> packed bf16x2, one v_perm_b32
__device__ __forceinline__ unsigned int pktrunc(float lo, float hi) {
    return __builtin_amdgcn_perm(__float_as_uint(hi), __float_as_uint(lo), 0x07060302u);
}
__device__ __forceinline__ float blo(unsigned int u) {
    return __uint_as_float(u << 16);
}
__device__ __forceinline__ float bhi(unsigned int u) {
    return __uint_as_float(u & 0xffff0000u);
}

// ---------------- convert: fp32 -> bf16 (phr,vis,W,U); also sgf[:, :512]=phr
#define PHR4 262144
#define VIS4 1048576
#define WW4  65536
#define UU4  131072
#define TOT4 (PHR4 + VIS4 + WW4 + UU4)   // 1,507,328 float4s

__global__ __launch_bounds__(256) void convert_bf16(
    const float* __restrict__ phr, const float* __restrict__ vis,
    const float* __restrict__ W,   const float* __restrict__ U,
    us* __restrict__ phr_b, us* __restrict__ vis_b,
    us* __restrict__ W_b,   us* __restrict__ U_b,
    float* __restrict__ out_sgf)
{
    int i = blockIdx.x * 256 + threadIdx.x;
    if (i >= TOT4) return;
    const float* src; us* dst; int o;
    if (i < PHR4)              { src = phr; dst = phr_b; o = i; }
    else if (i < PHR4 + VIS4)  { src = vis; dst = vis_b; o = i - PHR4; }
    else if (i < PHR4 + VIS4 + WW4) { src = W; dst = W_b; o = i - PHR4 - VIS4; }
    else                       { src = U; dst = U_b; o = i - PHR4 - VIS4 - WW4; }
    float4 v = ((const float4*)src)[o];
    uint2 r = { pktrunc(v.x, v.y), pktrunc(v.z, v.w) };
    *(uint2*)(dst + (size_t)o * 4) = r;
    if (i < PHR4) {   // concat left half: sgf[row, 0:512] = phr (fp32, exact)
        int row = o >> 7, c4 = o & 127;
        ((float4*)out_sgf)[(size_t)row * 384 + c4] = v;
    }
}

// ---------------- GEMM: 64x64 tile, BK=64, double-buffered 2-phase ----------
// Per K-step: issue next tile's global_load_lds FIRST, then ds_read+MFMA on
// current buffer, then ONE __syncthreads (its vmcnt drain lands after the
// compute -> load latency hidden). 32 MFMA per barrier.
// LDS layout: row-major [64][64] bf16 in 16B chunks; chunk at (row, lc) stored
// at phys = lc ^ (row&7) -> frag ds_read_b128 spreads uniformly over all 32
// banks (8 lanes/16B-granule = bandwidth floor). Inverse swizzle applied to
// the per-lane GLOBAL source; LDS dest linear (m173 pattern).
// mode Yq (whYp != null): C = exp2(CC*(acc+bias)) stored FP32 to whY[2048][512]
// mode Yv: C = exp2(CC*acc) stored bf16 TRANSPOSED to uvYT[b][n][v] via LDS
//   transpose (coalesced stores).
__device__ __forceinline__ void gemm64(
    us* smem,                             // 16384 us: two 8192-us buffers
    const us* __restrict__ A, const us* __restrict__ Bt,
    const float* __restrict__ bias,
    float* __restrict__ whYp, us* __restrict__ uvYTp,
    int K, int bx, int by)
{
    const int tid  = threadIdx.x;
    const int m0   = bx * 64;
    const int n0   = by * 64;
    const int wave = tid >> 6;
    const int lane = tid & 63;
    const int wm   = (wave >> 1) * 32;
    const int wn   = (wave & 1) * 32;
    const int fm   = lane & 15;
    const int c16  = lane >> 4;           // k-quarter within a 32-step

    // staging: thread covers chunk cid=tid (rows 0..31) and cid=256+tid
    // (rows 32..63). row1 = row0+32 -> same (row&7) -> same logical chunk lc.
    const int r0 = tid >> 3;              // 0..31
    const int lc = (tid & 7) ^ (r0 & 7);  // inverse swizzle -> source chunk
    const us* ga0 = A  + (size_t)(m0 + r0)      * K + lc * 8;
    const us* ga1 = A  + (size_t)(m0 + r0 + 32) * K + lc * 8;
    const us* gb0 = Bt + (size_t)(n0 + r0)      * K + lc * 8;
    const us* gb1 = Bt + (size_t)(n0 + r0 + 32) * K + lc * 8;
    const int dst0 = wave * 512;          // us offset, wave-uniform
    const int dst1 = 2048 + wave * 512;

    floatx4 acc[2][2] = {};
    const int nt = K >> 6;
    int cur = 0;

#define STAGE(bufbase, k0) do {                                                \
    us* as_ = (bufbase);  us* bs_ = (bufbase) + 4096;                          \
    __builtin_amdgcn_global_load_lds((gu32*)(ga0 + (k0)), (lu32*)(as_ + dst0), 16, 0, 0); \
    __builtin_amdgcn_global_load_lds((gu32*)(ga1 + (k0)), (lu32*)(as_ + dst1), 16, 0, 0); \
    __builtin_amdgcn_global_load_lds((gu32*)(gb0 + (k0)), (lu32*)(bs_ + dst0), 16, 0, 0); \
    __builtin_amdgcn_global_load_lds((gu32*)(gb1 + (k0)), (lu32*)(bs_ + dst1), 16, 0, 0); \
} while (0)

    STAGE(smem, 0);
    __syncthreads();                      // drain prologue stage
    for (int t = 0; t < nt; ++t) {
        us* As = smem + cur * 8192;
        us* Bs = As + 4096;
        if (t + 1 < nt) STAGE(smem + (cur ^ 1) * 8192, (t + 1) * 64);
        #pragma unroll
        for (int ks = 0; ks < 2; ++ks) {
            bf16x8 am[2], bn[2];
            #pragma unroll
            for (int i = 0; i < 2; ++i) {
                int r  = wm + 16 * i + fm;
                int pc = (ks * 4 + c16) ^ (r & 7);
                am[i] = *(const bf16x8*)(As + r * 64 + pc * 8);
            }
            #pragma unroll
            for (int j = 0; j < 2; ++j) {
                int r  = wn + 16 * j + fm;
                int pc = (ks * 4 + c16) ^ (r & 7);
                bn[j] = *(const bf16x8*)(Bs + r * 64 + pc * 8);
            }
            #pragma unroll
            for (int i = 0; i < 2; ++i)
                #pragma unroll
                for (int j = 0; j < 2; ++j)
                    acc[i][j] = __builtin_amdgcn_mfma_f32_16x16x32_bf16(am[i], bn[j], acc[i][j], 0, 0, 0);
        }
        __syncthreads();                  // drains next-tile loads AFTER compute
        cur ^= 1;
    }
#undef STAGE

    // C/D layout: col = lane&15, row = (lane>>4)*4 + reg
    const int cr = (lane >> 4) * 4;
    const int cc = lane & 15;
    if (whYp) {
        #pragma unroll
        for (int j = 0; j < 2; ++j) {
            int gn = n0 + wn + 16 * j + cc;
            float bj = bias[gn];
            #pragma unroll
            for (int i = 0; i < 2; ++i)
                #pragma unroll
                for (int r = 0; r < 4; ++r) {
                    int gm = m0 + wm + 16 * i + cr + r;
                    whYp[(size_t)gm * NBN + gn] =
                        __builtin_amdgcn_exp2f(CC * (acc[i][j][r] + bj));
                }
        }
    } else {
        // ---- LDS transpose epilogue: Cs[n_local][v_local], stride 72 us ----
        us* Cs = smem;                     // 64*72 = 4608 us, reuse staging
        #pragma unroll
        for (int i = 0; i < 2; ++i)
            #pragma unroll
            for (int j = 0; j < 2; ++j) {
                int nl = wn + 16 * j + cc;
                int vl = wm + 16 * i + cr;
                #pragma unroll
                for (int r = 0; r < 4; ++r)
                    Cs[nl * 72 + vl + r] =
                        f2bf(__builtin_amdgcn_exp2f(CC * acc[i][j][r]));
            }
        __syncthreads();
        const int bb    = m0 >> 7;         // batch
        const int vbase = m0 & 127;        // 0 or 64
        const int nl    = tid >> 2;        // 0..63
        const int vc    = (tid & 3) * 16;  // 16-v chunk
        uint4 t0 = *(const uint4*)(Cs + nl * 72 + vc);
        uint4 t1 = *(const uint4*)(Cs + nl * 72 + vc + 8);
        us* dst = uvYTp + ((size_t)bb * NBN + n0 + nl) * NLV + vbase + vc;
        *(uint4*)dst       = t0;
        *(uint4*)(dst + 8) = t1;
    }
}

// blocks 0..255: Yq (M=2048,K=512, nbx=32); 256..767: Yv (M=4096,K=1024, nbx=64)
__global__ __launch_bounds__(256) void gemm_both(
    const us* __restrict__ phr_b, const us* __restrict__ W_b,
    const float* __restrict__ bias,
    const us* __restrict__ vis_b, const us* __restrict__ U_b,
    float* __restrict__ whY, us* __restrict__ uvYT)
{
    __shared__ __align__(16) us smem[16384];   // 32 KB
    int blk = blockIdx.x;
    if (blk < 256) {
        int bx = blk % 32, by = blk / 32;
        gemm64(smem, phr_b, W_b, bias, whY, nullptr, NQS, bx, by);
    } else {
        blk -= 256;
        int bx = blk % 64, by = blk / 64;
        gemm64(smem, vis_b, U_b, bias, nullptr, uvYT, NFS, bx, by);
    }
}

// ---------------- energize: in-thread n-reduction, paired rcp ---------------
// block = (b, q-quad), 512 threads, 8 waves = n-eighths. lane owns v-pair.
//   w0/d0 + w1/d1 = (w0*d1 + w1*d0) / (d0*d1)   (d >= 1, overflow -> 0, safe)
__global__ __launch_bounds__(512) void energize(
    const float* __restrict__ whY,    // [2048][512] fp32 = exp(2(Wh+b))
    const us* __restrict__ uvYT,      // [32][512][128] bf16 = exp(2Uv), [n][v]
    const float* __restrict__ wvec,   // [512]
    float* __restrict__ out_w, float* __restrict__ out_e,
    us* __restrict__ p_bf, us* __restrict__ p_lo)   // [2048][128]
{
    const float LOG2E = 1.4426950408889634f;
    int blk = blockIdx.x;
    blk = (blk & 7) * 64 + (blk >> 3);    // bijective XCD swizzle (512 = 8*64)
    const int b    = blk >> 4;            // b-major: 16 blocks share uvYT[b]
    const int qq4  = blk & 15;
    const int tid  = threadIdx.x;
    const int wave = __builtin_amdgcn_readfirstlane(tid >> 6);  // n-eighth 0..7
    const int lane = tid & 63;
    const int q0   = qq4 * 4;

    __shared__ float part[4][8][NLV];     // [q][n-eighth][v] = 16 KB

    // sumw (once per wave)
    float4 sw0 = *(const float4*)(wvec + lane * 8);
    float4 sw1 = *(const float4*)(wvec + lane * 8 + 4);
    float sumw = sw0.x + sw0.y + sw0.z + sw0.w + sw1.x + sw1.y + sw1.z + sw1.w;
    #pragma unroll
    for (int off = 32; off; off >>= 1) sumw += __shfl_xor(sumw, off);

    const float* yqp = whY + (size_t)(b * NLQ + q0) * NBN + wave * 64;
    const float* wp  = wvec + wave * 64;
    const us*    uvp = uvYT + ((size_t)b * NBN + wave * 64) * NLV + 2 * lane;

    float acc[4][2] = {};
    #pragma unroll 2
    for (int nc = 0; nc < 64; nc += 8) {
        unsigned int yv[8];
        #pragma unroll
        for (int k = 0; k < 8; ++k)
            yv[k] = *(const unsigned int*)(uvp + (size_t)(nc + k) * NLV);
        #pragma unroll
        for (int kk = 0; kk < 4; ++kk) {
            const int k0 = nc + 2 * kk, k1 = k0 + 1;
            float x0a = blo(yv[2 * kk]),     x0b = bhi(yv[2 * kk]);     // n=k0
            float x1a = blo(yv[2 * kk + 1]), x1b = bhi(yv[2 * kk + 1]); // n=k1
            float w0 = wp[k0], w1 = wp[k1];                 // uniform -> SGPR
            #pragma unroll
            for (int q = 0; q < 4; ++q) {
                float y0 = yqp[q * NBN + k0];               // uniform -> SGPR
                float y1 = yqp[q * NBN + k1];
                float d0a = fmaf(x0a, y0, 1.f), d1a = fmaf(x1a, y1, 1.f);
                float d0b = fmaf(x0b, y0, 1.f), d1b = fmaf(x1b, y1, 1.f);
                float numa = fmaf(w0, d1a, w1 * d0a);
                float numb = fmaf(w0, d1b, w1 * d0b);
                acc[q][0] = fmaf(numa, __builtin_amdgcn_rcpf(d0a * d1a), acc[q][0]);
                acc[q][1] = fmaf(numb, __builtin_amdgcn_rcpf(d0b * d1b), acc[q][1]);
            }
        }
    }
    #pragma unroll
    for (int q = 0; q < 4; ++q) {
        float2 t = { acc[q][0], acc[q][1] };
        *(float2*)&part[q][wave][2 * lane] = t;
    }
    __syncthreads();

    // softmax: wave w handles q = w (4 q on waves 0..3)
    if (wave < 4) {
        const int q = wave;
        float s0 = 0.f, s1 = 0.f;
        #pragma unroll
        for (int nq = 0; nq < 8; ++nq) {
            s0 += part[q][nq][2 * lane];
            s1 += part[q][nq][2 * lane + 1];
        }
        float e0 = sumw - 2.f * s0;
        float e1 = sumw - 2.f * s1;
        float m = fmaxf(e0, e1);
        #pragma unroll
        for (int off = 32; off; off >>= 1) m = fmaxf(m, __shfl_xor(m, off));
        float x0 = __builtin_amdgcn_exp2f((e0 - m) * LOG2E);
        float x1 = __builtin_amdgcn_exp2f((e1 - m) * LOG2E);
        float ss = x0 + x1;
        #pragma unroll
        for (int off = 32; off; off >>= 1) ss += __shfl_xor(ss, off);
        float inv = __builtin_amdgcn_rcpf(ss);
        float p0 = x0 * inv, p1 = x1 * inv;

        const size_t row = (size_t)(b * NLQ + q0 + q);
        float2 ep = { e0, e1 };
        float2 pp = { p0, p1 };
        *(float2*)(out_e + row * NLV + 2 * lane) = ep;
        *(float2*)(out_w + row * NLV + 2 * lane) = pp;
        // bf16 p + bf16 correction (restores fp32 accuracy in the MFMA)
        unsigned int pb0 = f2bf(p0), pb1 = f2bf(p1);
        float lo0 = p0 - __uint_as_float(pb0 << 16);
        float lo1 = p1 - __uint_as_float(pb1 << 16);
        unsigned int lb0 = f2bf(lo0), lb1 = f2bf(lo1);
        *(unsigned int*)(p_bf + row * NLV + 2 * lane) = pb0 | (pb1 << 16);
        *(unsigned int*)(p_lo + row * NLV + 2 * lane) = lb0 | (lb1 << 16);
    }
}

// ---------------- aligned via MFMA: out = (P + P_lo) . V ---------------------
// block = (b, f-tile of 64). Stages its V slice from bf16 vis_b (half the
// fetch of fp32 vis; identical truncation numerics), LDS-transposed to
// Vs[f][v] (pad 136). A-frags (P) from L2; B-frags from LDS.
__global__ __launch_bounds__(256) void aligned_mfma(
    const us* __restrict__ p_bf, const us* __restrict__ p_lo,  // [2048][128]
    const us* __restrict__ vis_b,                              // [32][128][1024]
    float* __restrict__ out_sgf)
{
    int blk = blockIdx.x;
    blk = (blk & 7) * 64 + (blk >> 3);    // XCD swizzle, b-major
    const int b    = blk >> 4;
    const int ft   = blk & 15;
    const int tid  = threadIdx.x;
    const int wave = tid >> 6;
    const int lane = tid & 63;
    const int wm   = (wave >> 1) * 32;    // q offset
    const int wf   = (wave & 1) * 32;     // f offset within the 64-tile
    const int fm   = lane & 15;
    const int fko  = (lane >> 4) * 8;

    __shared__ us Vs[64][136];            // [f][v], row stride 272 B

    {   // stage V: thread owns (v = tid>>1, f-half = (tid&1)*32)
        const int v  = tid >> 1;
        const int fh = (tid & 1) * 32;
        const us* vp = vis_b + ((size_t)b * NLV + v) * NFS + ft * 64 + fh;
        #pragma unroll
        for (int r = 0; r < 8; ++r) {
            uint2 u = *(const uint2*)(vp + 4 * r);
            Vs[fh + 4 * r + 0][v] = (us)(u.x & 0xffffu);
            Vs[fh + 4 * r + 1][v] = (us)(u.x >> 16);
            Vs[fh + 4 * r + 2][v] = (us)(u.y & 0xffffu);
            Vs[fh + 4 * r + 3][v] = (us)(u.y >> 16);
        }
    }
    __syncthreads();

    floatx4 acc[2][2] = {};
    const us* pA  = p_bf + ((size_t)b * NLQ + wm + fm) * NLV + fko;
    const us* pAl = p_lo + ((size_t)b * NLQ + wm + fm) * NLV + fko;

    #pragma unroll
    for (int ks = 0; ks < 4; ++ks) {
        bf16x8 a[2], al[2], bb2[2];
        #pragma unroll
        for (int i = 0; i < 2; ++i) {
            a[i]  = *(const bf16x8*)(pA  + (size_t)i * 16 * NLV + ks * 32);
            al[i] = *(const bf16x8*)(pAl + (size_t)i * 16 * NLV + ks * 32);
        }
        #pragma unroll
        for (int j = 0; j < 2; ++j)
            bb2[j] = *(const bf16x8*)&Vs[wf + 16 * j + fm][ks * 32 + fko];
        #pragma unroll
        for (int i = 0; i < 2; ++i)
            #pragma unroll
            for (int j = 0; j < 2; ++j) {
                acc[i][j] = __builtin_amdgcn_mfma_f32_16x16x32_bf16(a[i],  bb2[j], acc[i][j], 0, 0, 0);
                acc[i][j] = __builtin_amdgcn_mfma_f32_16x16x32_bf16(al[i], bb2[j], acc[i][j], 0, 0, 0);
            }
    }

    const int cr = (lane >> 4) * 4;
    const int cc = lane & 15;
    #pragma unroll
    for (int i = 0; i < 2; ++i)
        #pragma unroll
        for (int j = 0; j < 2; ++j)
            #pragma unroll
            for (int r = 0; r < 4; ++r) {
                int q = wm + 16 * i + cr + r;
                int f = ft * 64 + wf + 16 * j + cc;
                size_t row = (size_t)b * NLQ + q;
                out_sgf[row * (NQS + NFS) + NQS + f] = acc[i][j][r];
            }
}

extern "C" void kernel_launch(void* const* d_in, const int* in_sizes, int n_in,
                              void* d_out, int out_size, void* d_ws, size_t ws_size,
                              hipStream_t stream) {
    const float* phr  = (const float*)d_in[0];
    const float* vis  = (const float*)d_in[1];
    const float* W    = (const float*)d_in[2];
    const float* U    = (const float*)d_in[3];
    const float* bias = (const float*)d_in[4];
    const float* wvec = (const float*)d_in[5];

    char* ws = (char*)d_ws;
    us* phr_b   = (us*)ws;                          // 2 MB
    us* vis_b   = (us*)(ws + (2u << 20));           // 8 MB
    us* W_b     = (us*)(ws + (10u << 20));          // 0.5 MB
    us* U_b     = (us*)(ws + (10u << 20) + (512u << 10));   // 1 MB
    float* whY  = (float*)(ws + (12u << 20));       // 4 MB [2048][512] fp32
    us* uvYT    = (us*)(ws + (16u << 20));          // 4 MB [32][512][128] bf16
    us* p_bf    = (us*)(ws + (20u << 20));          // 512 KB [2048][128]
    us* p_lo    = (us*)(ws + (20u << 20) + (512u << 10));   // 512 KB

    float* out     = (float*)d_out;
    float* out_sgf = out;
    float* out_w   = out_sgf + (size_t)NB * NLQ * (NQS + NFS);
    float* out_e   = out_w   + (size_t)NB * NLQ * NLV;

    convert_bf16<<<TOT4 / 256, 256, 0, stream>>>(
        phr, vis, W, U, phr_b, vis_b, W_b, U_b, out_sgf);
    gemm_both<<<768, 256, 0, stream>>>(phr_b, W_b, bias, vis_b, U_b, whY, uvYT);
    energize<<<512, 512, 0, stream>>>(whY, uvYT, wvec, out_w, out_e, p_bf, p_lo);
    aligned_mfma<<<512, 256, 0, stream>>>(p_bf, p_lo, vis_b, out_sgf);
}

// Round 9
// 117.126 us; speedup vs baseline: 1.0704x; 1.0147x over previous
//
#include <hip/hip_runtime.h>

#define NB  32
#define NLQ 64
#define NLV 128
#define NQS 512
#define NFS 1024
#define NBN 512
#define CC  2.8853900817779268f   // 2*log2(e):  exp(2x) = exp2(CC*x)

typedef float  floatx4 __attribute__((ext_vector_type(4)));
typedef __bf16 bf16x8  __attribute__((ext_vector_type(8)));
typedef unsigned short us;
typedef __attribute__((address_space(1))) const unsigned int gu32;
typedef __attribute__((address_space(3))) unsigned int lu32;

__device__ __forceinline__ us f2bf(float f) {
    unsigned int u = __float_as_uint(f);
    u += 0x7fffu + ((u >> 16) & 1u);   // round-to-nearest-even
    return (us)(u >> 16);
}
// truncating pack of two fp32 -> packed bf16x2, one v_perm_b32
__device__ __forceinline__ unsigned int pktrunc(float lo, float hi) {
    return __builtin_amdgcn_perm(__float_as_uint(hi), __float_as_uint(lo), 0x07060302u);
}
__device__ __forceinline__ float blo(unsigned int u) {
    return __uint_as_float(u << 16);
}
__device__ __forceinline__ float bhi(unsigned int u) {
    return __uint_as_float(u & 0xffff0000u);
}

// ---------------- convert: fp32 -> bf16 (phr,vis,W,U); also sgf[:, :512]=phr
#define PHR4 262144
#define VIS4 1048576
#define WW4  65536
#define UU4  131072
#define TOT4 (PHR4 + VIS4 + WW4 + UU4)   // 1,507,328 float4s

__global__ __launch_bounds__(256) void convert_bf16(
    const float* __restrict__ phr, const float* __restrict__ vis,
    const float* __restrict__ W,   const float* __restrict__ U,
    us* __restrict__ phr_b, us* __restrict__ vis_b,
    us* __restrict__ W_b,   us* __restrict__ U_b,
    float* __restrict__ out_sgf)
{
    int i = blockIdx.x * 256 + threadIdx.x;
    if (i >= TOT4) return;
    const float* src; us* dst; int o;
    if (i < PHR4)              { src = phr; dst = phr_b; o = i; }
    else if (i < PHR4 + VIS4)  { src = vis; dst = vis_b; o = i - PHR4; }
    else if (i < PHR4 + VIS4 + WW4) { src = W; dst = W_b; o = i - PHR4 - VIS4; }
    else                       { src = U; dst = U_b; o = i - PHR4 - VIS4 - WW4; }
    float4 v = ((const float4*)src)[o];
    uint2 r = { pktrunc(v.x, v.y), pktrunc(v.z, v.w) };
    *(uint2*)(dst + (size_t)o * 4) = r;
    if (i < PHR4) {   // concat left half: sgf[row, 0:512] = phr (fp32, exact)
        int row = o >> 7, c4 = o & 127;
        ((float4*)out_sgf)[(size_t)row * 384 + c4] = v;
    }
}

// ---------------- GEMM: 64x64 tile, BK=64, 3-buffer counted-vmcnt pipeline --
// Prefetch distance 2: tiles t+1, t+2 stay in flight across barriers (vmcnt(8)
// steady state, never drained to 0 in the main loop -> load latency gets a
// full iteration (~800 cyc) to complete instead of ~400 (T3/T4 pattern).
// Per iter: s_barrier (overwrite-safe) -> STAGE(t+2) -> vmcnt(8|4|0) (own
// tile-t loads done) -> s_barrier (all waves' loads done) -> sched_barrier ->
// ds_read + 32 MFMA.
// LDS layout per buffer: [64][64] bf16 in 16B chunks; chunk (row, lc) at
// phys = lc ^ (row&7); inverse swizzle on the per-lane GLOBAL source, LDS
// dest linear (m173 pattern) -> conflict-free ds_read_b128 frags.
// mode Yq (whYp != null): C = exp2(CC*(acc+bias)) stored FP32 to whY[2048][512]
// mode Yv: C = exp2(CC*acc) stored bf16 TRANSPOSED to uvYT[b][n][v] via LDS
//   transpose (coalesced stores).
__device__ __forceinline__ void gemm64(
    us* smem,                             // 24576 us: three 8192-us buffers
    const us* __restrict__ A, const us* __restrict__ Bt,
    const float* __restrict__ bias,
    float* __restrict__ whYp, us* __restrict__ uvYTp,
    int K, int bx, int by)
{
    const int tid  = threadIdx.x;
    const int m0   = bx * 64;
    const int n0   = by * 64;
    const int wave = tid >> 6;
    const int lane = tid & 63;
    const int wm   = (wave >> 1) * 32;
    const int wn   = (wave & 1) * 32;
    const int fm   = lane & 15;
    const int c16  = lane >> 4;           // k-quarter within a 32-step

    // staging: thread covers chunk cid=tid (rows 0..31) and cid=256+tid
    // (rows 32..63). row1 = row0+32 -> same (row&7) -> same logical chunk lc.
    const int r0 = tid >> 3;              // 0..31
    const int lc = (tid & 7) ^ (r0 & 7);  // inverse swizzle -> source chunk
    const us* ga0 = A  + (size_t)(m0 + r0)      * K + lc * 8;
    const us* ga1 = A  + (size_t)(m0 + r0 + 32) * K + lc * 8;
    const us* gb0 = Bt + (size_t)(n0 + r0)      * K + lc * 8;
    const us* gb1 = Bt + (size_t)(n0 + r0 + 32) * K + lc * 8;
    const int dst0 = wave * 512;          // us offset, wave-uniform
    const int dst1 = 2048 + wave * 512;

    floatx4 acc[2][2] = {};
    const int nt = K >> 6;                // 8 (Yq) or 16 (Yv)

#define STAGE(bufbase, k0) do {                                                \
    us* as_ = (bufbase);  us* bs_ = (bufbase) + 4096;                          \
    __builtin_amdgcn_global_load_lds((gu32*)(ga0 + (k0)), (lu32*)(as_ + dst0), 16, 0, 0); \
    __builtin_amdgcn_global_load_lds((gu32*)(ga1 + (k0)), (lu32*)(as_ + dst1), 16, 0, 0); \
    __builtin_amdgcn_global_load_lds((gu32*)(gb0 + (k0)), (lu32*)(bs_ + dst0), 16, 0, 0); \
    __builtin_amdgcn_global_load_lds((gu32*)(gb1 + (k0)), (lu32*)(bs_ + dst1), 16, 0, 0); \
} while (0)

    STAGE(smem, 0);                       // tile 0 -> buf 0
    STAGE(smem + 8192, 64);               // tile 1 -> buf 1
    int rs = 0;                           // read slot = t % 3
    for (int t = 0; t < nt; ++t) {
        us* As = smem + rs * 8192;
        us* Bs = As + 4096;
        // all waves finished reading buf[(t-1)%3] == the slot STAGE will hit
        __builtin_amdgcn_s_barrier();
        __builtin_amdgcn_sched_barrier(0);
        if (t + 2 < nt) {
            int ss = rs + 2; if (ss >= 3) ss -= 3;
            STAGE(smem + ss * 8192, (t + 2) * 64);
            asm volatile("s_waitcnt vmcnt(8)" ::: "memory");   // own t-loads done
        } else if (t + 1 < nt) {
            asm volatile("s_waitcnt vmcnt(4)" ::: "memory");
        } else {
            asm volatile("s_waitcnt vmcnt(0)" ::: "memory");
        }
        __builtin_amdgcn_s_barrier();     // every wave's t-loads landed
        __builtin_amdgcn_sched_barrier(0);
        #pragma unroll
        for (int ks = 0; ks < 2; ++ks) {
            bf16x8 am[2], bn[2];
            #pragma unroll
            for (int i = 0; i < 2; ++i) {
                int r  = wm + 16 * i + fm;
                int pc = (ks * 4 + c16) ^ (r & 7);
                am[i] = *(const bf16x8*)(As + r * 64 + pc * 8);
            }
            #pragma unroll
            for (int j = 0; j < 2; ++j) {
                int r  = wn + 16 * j + fm;
                int pc = (ks * 4 + c16) ^ (r & 7);
                bn[j] = *(const bf16x8*)(Bs + r * 64 + pc * 8);
            }
            #pragma unroll
            for (int i = 0; i < 2; ++i)
                #pragma unroll
                for (int j = 0; j < 2; ++j)
                    acc[i][j] = __builtin_amdgcn_mfma_f32_16x16x32_bf16(am[i], bn[j], acc[i][j], 0, 0, 0);
        }
        rs = (rs == 2) ? 0 : rs + 1;
    }
#undef STAGE

    // C/D layout: col = lane&15, row = (lane>>4)*4 + reg
    const int cr = (lane >> 4) * 4;
    const int cc = lane & 15;
    if (whYp) {
        #pragma unroll
        for (int j = 0; j < 2; ++j) {
            int gn = n0 + wn + 16 * j + cc;
            float bj = bias[gn];
            #pragma unroll
            for (int i = 0; i < 2; ++i)
                #pragma unroll
                for (int r = 0; r < 4; ++r) {
                    int gm = m0 + wm + 16 * i + cr + r;
                    whYp[(size_t)gm * NBN + gn] =
                        __builtin_amdgcn_exp2f(CC * (acc[i][j][r] + bj));
                }
        }
    } else {
        // ---- LDS transpose epilogue: Cs[n_local][v_local], stride 72 us ----
        us* Cs = smem;                     // reuse staging
        __syncthreads();                   // all waves out of the K-loop LDS
        #pragma unroll
        for (int i = 0; i < 2; ++i)
            #pragma unroll
            for (int j = 0; j < 2; ++j) {
                int nl = wn + 16 * j + cc;
                int vl = wm + 16 * i + cr;
                #pragma unroll
                for (int r = 0; r < 4; ++r)
                    Cs[nl * 72 + vl + r] =
                        f2bf(__builtin_amdgcn_exp2f(CC * acc[i][j][r]));
            }
        __syncthreads();
        const int bb    = m0 >> 7;         // batch
        const int vbase = m0 & 127;        // 0 or 64
        const int nl    = tid >> 2;        // 0..63
        const int vc    = (tid & 3) * 16;  // 16-v chunk
        uint4 t0 = *(const uint4*)(Cs + nl * 72 + vc);
        uint4 t1 = *(const uint4*)(Cs + nl * 72 + vc + 8);
        us* dst = uvYTp + ((size_t)bb * NBN + n0 + nl) * NLV + vbase + vc;
        *(uint4*)dst       = t0;
        *(uint4*)(dst + 8) = t1;
    }
}

// blocks 0..255: Yq (M=2048,K=512, nbx=32); 256..767: Yv (M=4096,K=1024, nbx=64)
__global__ __launch_bounds__(256) void gemm_both(
    const us* __restrict__ phr_b, const us* __restrict__ W_b,
    const float* __restrict__ bias,
    const us* __restrict__ vis_b, const us* __restrict__ U_b,
    float* __restrict__ whY, us* __restrict__ uvYT)
{
    __shared__ __align__(16) us smem[24576];   // 48 KB -> 3 blocks/CU
    int blk = blockIdx.x;
    if (blk < 256) {
        int bx = blk % 32, by = blk / 32;
        gemm64(smem, phr_b, W_b, bias, whY, nullptr, NQS, bx, by);
    } else {
        blk -= 256;
        int bx = blk % 64, by = blk / 64;
        gemm64(smem, vis_b, U_b, bias, nullptr, uvYT, NFS, bx, by);
    }
}

// ---------------- energize: in-thread n-reduction, paired rcp ---------------
// block = (b, q-quad), 512 threads, 8 waves = n-eighths. lane owns v-pair.
//   w0/d0 + w1/d1 = (w0*d1 + w1*d0) / (d0*d1)   (d >= 1, overflow -> 0, safe)
__global__ __launch_bounds__(512) void energize(
    const float* __restrict__ whY,    // [2048][512] fp32 = exp(2(Wh+b))
    const us* __restrict__ uvYT,      // [32][512][128] bf16 = exp(2Uv), [n][v]
    const float* __restrict__ wvec,   // [512]
    float* __restrict__ out_w, float* __restrict__ out_e,
    us* __restrict__ p_bf, us* __restrict__ p_lo)   // [2048][128]
{
    const float LOG2E = 1.4426950408889634f;
    int blk = blockIdx.x;
    blk = (blk & 7) * 64 + (blk >> 3);    // bijective XCD swizzle (512 = 8*64)
    const int b    = blk >> 4;            // b-major: 16 blocks share uvYT[b]
    const int qq4  = blk & 15;
    const int tid  = threadIdx.x;
    const int wave = __builtin_amdgcn_readfirstlane(tid >> 6);  // n-eighth 0..7
    const int lane = tid & 63;
    const int q0   = qq4 * 4;

    __shared__ float part[4][8][NLV];     // [q][n-eighth][v] = 16 KB

    // sumw (once per wave)
    float4 sw0 = *(const float4*)(wvec + lane * 8);
    float4 sw1 = *(const float4*)(wvec + lane * 8 + 4);
    float sumw = sw0.x + sw0.y + sw0.z + sw0.w + sw1.x + sw1.y + sw1.z + sw1.w;
    #pragma unroll
    for (int off = 32; off; off >>= 1) sumw += __shfl_xor(sumw, off);

    const float* yqp = whY + (size_t)(b * NLQ + q0) * NBN + wave * 64;
    const float* wp  = wvec + wave * 64;
    const us*    uvp = uvYT + ((size_t)b * NBN + wave * 64) * NLV + 2 * lane;

    float acc[4][2] = {};
    #pragma unroll 2
    for (int nc = 0; nc < 64; nc += 8) {
        unsigned int yv[8];
        #pragma unroll
        for (int k = 0; k < 8; ++k)
            yv[k] = *(const unsigned int*)(uvp + (size_t)(nc + k) * NLV);
        #pragma unroll
        for (int kk = 0; kk < 4; ++kk) {
            const int k0 = nc + 2 * kk, k1 = k0 + 1;
            float x0a = blo(yv[2 * kk]),     x0b = bhi(yv[2 * kk]);     // n=k0
            float x1a = blo(yv[2 * kk + 1]), x1b = bhi(yv[2 * kk + 1]); // n=k1
            float w0 = wp[k0], w1 = wp[k1];                 // uniform -> SGPR
            #pragma unroll
            for (int q = 0; q < 4; ++q) {
                float y0 = yqp[q * NBN + k0];               // uniform -> SGPR
                float y1 = yqp[q * NBN + k1];
                float d0a = fmaf(x0a, y0, 1.f), d1a = fmaf(x1a, y1, 1.f);
                float d0b = fmaf(x0b, y0, 1.f), d1b = fmaf(x1b, y1, 1.f);
                float numa = fmaf(w0, d1a, w1 * d0a);
                float numb = fmaf(w0, d1b, w1 * d0b);
                acc[q][0] = fmaf(numa, __builtin_amdgcn_rcpf(d0a * d1a), acc[q][0]);
                acc[q][1] = fmaf(numb, __builtin_amdgcn_rcpf(d0b * d1b), acc[q][1]);
            }
        }
    }
    #pragma unroll
    for (int q = 0; q < 4; ++q) {
        float2 t = { acc[q][0], acc[q][1] };
        *(float2*)&part[q][wave][2 * lane] = t;
    }
    __syncthreads();

    // softmax: wave w handles q = w (4 q on waves 0..3)
    if (wave < 4) {
        const int q = wave;
        float s0 = 0.f, s1 = 0.f;
        #pragma unroll
        for (int nq = 0; nq < 8; ++nq) {
            s0 += part[q][nq][2 * lane];
            s1 += part[q][nq][2 * lane + 1];
        }
        float e0 = sumw - 2.f * s0;
        float e1 = sumw - 2.f * s1;
        float m = fmaxf(e0, e1);
        #pragma unroll
        for (int off = 32; off; off >>= 1) m = fmaxf(m, __shfl_xor(m, off));
        float x0 = __builtin_amdgcn_exp2f((e0 - m) * LOG2E);
        float x1 = __builtin_amdgcn_exp2f((e1 - m) * LOG2E);
        float ss = x0 + x1;
        #pragma unroll
        for (int off = 32; off; off >>= 1) ss += __shfl_xor(ss, off);
        float inv = __builtin_amdgcn_rcpf(ss);
        float p0 = x0 * inv, p1 = x1 * inv;

        const size_t row = (size_t)(b * NLQ + q0 + q);
        float2 ep = { e0, e1 };
        float2 pp = { p0, p1 };
        *(float2*)(out_e + row * NLV + 2 * lane) = ep;
        *(float2*)(out_w + row * NLV + 2 * lane) = pp;
        // bf16 p + bf16 correction (restores fp32 accuracy in the MFMA)
        unsigned int pb0 = f2bf(p0), pb1 = f2bf(p1);
        float lo0 = p0 - __uint_as_float(pb0 << 16);
        float lo1 = p1 - __uint_as_float(pb1 << 16);
        unsigned int lb0 = f2bf(lo0), lb1 = f2bf(lo1);
        *(unsigned int*)(p_bf + row * NLV + 2 * lane) = pb0 | (pb1 << 16);
        *(unsigned int*)(p_lo + row * NLV + 2 * lane) = lb0 | (lb1 << 16);
    }
}

// ---------------- aligned via MFMA: out = (P + P_lo) . V ---------------------
// block = (b, f-tile of 64). Stages its V slice from bf16 vis_b (half the
// fetch of fp32 vis; identical truncation numerics), LDS-transposed to
// Vs[f][v] (pad 136). A-frags (P) from L2; B-frags from LDS.
__global__ __launch_bounds__(256) void aligned_mfma(
    const us* __restrict__ p_bf, const us* __restrict__ p_lo,  // [2048][128]
    const us* __restrict__ vis_b,                              // [32][128][1024]
    float* __restrict__ out_sgf)
{
    int blk = blockIdx.x;
    blk = (blk & 7) * 64 + (blk >> 3);    // XCD swizzle, b-major
    const int b    = blk >> 4;
    const int ft   = blk & 15;
    const int tid  = threadIdx.x;
    const int wave = tid >> 6;
    const int lane = tid & 63;
    const int wm   = (wave >> 1) * 32;    // q offset
    const int wf   = (wave & 1) * 32;     // f offset within the 64-tile
    const int fm   = lane & 15;
    const int fko  = (lane >> 4) * 8;

    __shared__ us Vs[64][136];            // [f][v], row stride 272 B

    {   // stage V: thread owns (v = tid>>1, f-half = (tid&1)*32)
        const int v  = tid >> 1;
        const int fh = (tid & 1) * 32;
        const us* vp = vis_b + ((size_t)b * NLV + v) * NFS + ft * 64 + fh;
        #pragma unroll
        for (int r = 0; r < 8; ++r) {
            uint2 u = *(const uint2*)(vp + 4 * r);
            Vs[fh + 4 * r + 0][v] = (us)(u.x & 0xffffu);
            Vs[fh + 4 * r + 1][v] = (us)(u.x >> 16);
            Vs[fh + 4 * r + 2][v] = (us)(u.y & 0xffffu);
            Vs[fh + 4 * r + 3][v] = (us)(u.y >> 16);
        }
    }
    __syncthreads();

    floatx4 acc[2][2] = {};
    const us* pA  = p_bf + ((size_t)b * NLQ + wm + fm) * NLV + fko;
    const us* pAl = p_lo + ((size_t)b * NLQ + wm + fm) * NLV + fko;

    #pragma unroll
    for (int ks = 0; ks < 4; ++ks) {
        bf16x8 a[2], al[2], bb2[2];
        #pragma unroll
        for (int i = 0; i < 2; ++i) {
            a[i]  = *(const bf16x8*)(pA  + (size_t)i * 16 * NLV + ks * 32);
            al[i] = *(const bf16x8*)(pAl + (size_t)i * 16 * NLV + ks * 32);
        }
        #pragma unroll
        for (int j = 0; j < 2; ++j)
            bb2[j] = *(const bf16x8*)&Vs[wf + 16 * j + fm][ks * 32 + fko];
        #pragma unroll
        for (int i = 0; i < 2; ++i)
            #pragma unroll
            for (int j = 0; j < 2; ++j) {
                acc[i][j] = __builtin_amdgcn_mfma_f32_16x16x32_bf16(a[i],  bb2[j], acc[i][j], 0, 0, 0);
                acc[i][j] = __builtin_amdgcn_mfma_f32_16x16x32_bf16(al[i], bb2[j], acc[i][j], 0, 0, 0);
            }
    }

    const int cr = (lane >> 4) * 4;
    const int cc = lane & 15;
    #pragma unroll
    for (int i = 0; i < 2; ++i)
        #pragma unroll
        for (int j = 0; j < 2; ++j)
            #pragma unroll
            for (int r = 0; r < 4; ++r) {
                int q = wm + 16 * i + cr + r;
                int f = ft * 64 + wf + 16 * j + cc;
                size_t row = (size_t)b * NLQ + q;
                out_sgf[row * (NQS + NFS) + NQS + f] = acc[i][j][r];
            }
}

extern "C" void kernel_launch(void* const* d_in, const int* in_sizes, int n_in,
                              void* d_out, int out_size, void* d_ws, size_t ws_size,
                              hipStream_t stream) {
    const float* phr  = (const float*)d_in[0];
    const float* vis  = (const float*)d_in[1];
    const float* W    = (const float*)d_in[2];
    const float* U    = (const float*)d_in[3];
    const float* bias = (const float*)d_in[4];
    const float* wvec = (const float*)d_in[5];

    char* ws = (char*)d_ws;
    us* phr_b   = (us*)ws;                          // 2 MB
    us* vis_b   = (us*)(ws + (2u << 20));           // 8 MB
    us* W_b     = (us*)(ws + (10u << 20));          // 0.5 MB
    us* U_b     = (us*)(ws + (10u << 20) + (512u << 10));   // 1 MB
    float* whY  = (float*)(ws + (12u << 20));       // 4 MB [2048][512] fp32
    us* uvYT    = (us*)(ws + (16u << 20));          // 4 MB [32][512][128] bf16
    us* p_bf    = (us*)(ws + (20u << 20));          // 512 KB [2048][128]
    us* p_lo    = (us*)(ws + (20u << 20) + (512u << 10));   // 512 KB

    float* out     = (float*)d_out;
    float* out_sgf = out;
    float* out_w   = out_sgf + (size_t)NB * NLQ * (NQS + NFS);
    float* out_e   = out_w   + (size_t)NB * NLQ * NLV;

    convert_bf16<<<TOT4 / 256, 256, 0, stream>>>(
        phr, vis, W, U, phr_b, vis_b, W_b, U_b, out_sgf);
    gemm_both<<<768, 256, 0, stream>>>(phr_b, W_b, bias, vis_b, U_b, whY, uvYT);
    energize<<<512, 512, 0, stream>>>(whY, uvYT, wvec, out_w, out_e, p_bf, p_lo);
    aligned_mfma<<<512, 256, 0, stream>>>(p_bf, p_lo, vis_b, out_sgf);
}